// Round 11
// baseline (597.375 us; speedup 1.0000x reference)
//
#include <hip/hip_runtime.h>
#include <hip/hip_cooperative_groups.h>
#include <hip/hip_bf16.h>
#include <math.h>

namespace cg = cooperative_groups;

#define N_NODES 20000
#define N_EDGES 320000
#define ET (N_EDGES + N_NODES)   // 340000
#define IN_C 512
#define HEADS 8
#define HID 32
#define HH (HEADS * HID)         // 256
#define OUT_C 40
#define NEG_SLOPE 0.2f

#define MAX_GRID 1024            // 4 blocks/CU x 256 CUs
#define GEMM_VB 626              // 2 x 313 gemm tiles
#define COUNT_VB ((ET + 255) / 256)   // 1329
#define FILL_VB ((ET + 255) / 256)    // 1329
#define ATTN_VB (N_NODES / 4)         // 5000
#define L1_TILES (N_NODES / 16)       // 1250
#define AGG2_VB (N_NODES / 4)         // 5000

typedef __attribute__((ext_vector_type(8))) short short8;
typedef __attribute__((ext_vector_type(4))) float floatx4;

static __device__ __forceinline__ unsigned short f2bf(float f) {
  __hip_bfloat16 h = __float2bfloat16(f);
  return *(unsigned short*)&h;
}
static __device__ __forceinline__ float bf2f_lo(unsigned int u) {
  return __uint_as_float(u << 16);
}
static __device__ __forceinline__ float bf2f_hi(unsigned int u) {
  return __uint_as_float(u & 0xFFFF0000u);
}

struct Args {
  const float* x; const int* ei;
  const float* w1; const float* asrc1; const float* adst1; const float* b1;
  const float* w2; const float* asrc2; const float* adst2; const float* b2;
  float* out;
  float* as1; float* ad1; float* h3; float* as2; float* ad2;
  unsigned short* h1b; unsigned short* wbT; unsigned short* w2bT;
  int* deg; int* offs; int* cursor; int* csr;
};

// ---------------- P0: zero deg + convert w1 / w2 (transposed) ----------------
static __device__ __forceinline__ void phase_prep(const Args& a, int bid, int tid) {
  for (int gt = bid * 256 + tid; gt < IN_C * HH + HH * OUT_C;
       gt += gridDim.x * 256) {
    if (gt < N_NODES) a.deg[gt] = 0;
    if (gt < IN_C * HH) {
      int k = gt >> 8, n = gt & 255;           // coalesced w1 read
      a.wbT[(size_t)n * IN_C + k] = f2bf(a.w1[gt]);
    } else {
      int j = gt - IN_C * HH;                  // < 10240
      int k = j / OUT_C, oc = j % OUT_C;
      a.w2bT[oc * HH + k] = f2bf(a.w2[j]);
    }
  }
}

// ---------------- P1: GEMM1 tiles + edge count (virtual blocks) --------------
static __device__ void phase_gemm_count(const Args& a, int bid, int tid) {
  __shared__ unsigned short As[64][40];
  __shared__ unsigned short Bs[128][40];
  for (int vb = bid; vb < GEMM_VB + COUNT_VB; vb += gridDim.x) {
    if (vb < GEMM_VB) {
      const int lane = tid & 63, wave = tid >> 6;
      const int wm = (wave & 1) * 32;
      const int wn = (wave >> 1) * 64;
      const int r16 = lane & 15, q = lane >> 4;
      const int rowBase = (vb >> 1) * 64;
      const int colBase = (vb & 1) * 128;
      floatx4 acc[2][4] = {};
      for (int k0 = 0; k0 < IN_C; k0 += 32) {
        {
          int row = tid >> 2, kc = (tid & 3) * 8;
          int arow = rowBase + row;
          float4 v0 = make_float4(0.f, 0.f, 0.f, 0.f), v1 = v0;
          if (arow < N_NODES) {
            const float* p = a.x + (size_t)arow * IN_C + k0 + kc;
            v0 = *(const float4*)p;
            v1 = *(const float4*)(p + 4);
          }
          unsigned short tmp[8] = {f2bf(v0.x), f2bf(v0.y), f2bf(v0.z), f2bf(v0.w),
                                   f2bf(v1.x), f2bf(v1.y), f2bf(v1.z), f2bf(v1.w)};
          *(float4*)&As[row][kc] = *(const float4*)tmp;
        }
#pragma unroll
        for (int i = 0; i < 2; i++) {
          int c = tid + i * 256;
          int row = c >> 2, kc = (c & 3) * 8;
          float4 v = *(const float4*)(a.wbT + (size_t)(colBase + row) * IN_C + k0 + kc);
          *(float4*)&Bs[row][kc] = v;
        }
        __syncthreads();
        short8 afrag[2], bfrag[4];
#pragma unroll
        for (int mt = 0; mt < 2; mt++)
          afrag[mt] = *(const short8*)&As[wm + mt * 16 + r16][q * 8];
#pragma unroll
        for (int nt = 0; nt < 4; nt++)
          bfrag[nt] = *(const short8*)&Bs[wn + nt * 16 + r16][q * 8];
#pragma unroll
        for (int mt = 0; mt < 2; mt++)
#pragma unroll
          for (int nt = 0; nt < 4; nt++)
            acc[mt][nt] = __builtin_amdgcn_mfma_f32_16x16x32_bf16(
                afrag[mt], bfrag[nt], acc[mt][nt], 0, 0, 0);
        __syncthreads();
      }
#pragma unroll
      for (int mt = 0; mt < 2; mt++) {
#pragma unroll
        for (int nt = 0; nt < 4; nt++) {
          int col = colBase + wn + nt * 16 + r16;
          float bb = a.b1[col];
#pragma unroll
          for (int r = 0; r < 4; r++) {
            int row = rowBase + wm + mt * 16 + q * 4 + r;
            if (row < N_NODES)
              a.h1b[(size_t)row * HH + col] = f2bf(acc[mt][nt][r] + bb);
          }
        }
      }
    } else {
      int e = (vb - GEMM_VB) * 256 + tid;
      if (e < ET) {
        int dst = (e < N_EDGES) ? a.ei[N_EDGES + e] : (e - N_EDGES);
        atomicAdd(&a.deg[dst], 1);
      }
    }
  }
}

// ---------------- P2: CSR exclusive scan (single block) ----------------------
static __device__ void phase_scan(const Args& a, int t) {
  __shared__ int wsum[4];
  int4 buf[20];
  int s = 0;
  if (t < 250) {
    const int4* dp = (const int4*)a.deg + t * 20;
#pragma unroll
    for (int i = 0; i < 20; i++) {
      buf[i] = dp[i];
      s += buf[i].x + buf[i].y + buf[i].z + buf[i].w;
    }
  }
  int lane = t & 63, w = t >> 6;
  int inc = s;
  for (int o = 1; o < 64; o <<= 1) {
    int u = __shfl_up(inc, o, 64);
    if (lane >= o) inc += u;
  }
  if (lane == 63) wsum[w] = inc;
  __syncthreads();
  int waveOff = 0;
  for (int i = 0; i < w; i++) waveOff += wsum[i];
  int running = waveOff + inc - s;
  if (t < 250) {
    int base = t * 80;
#pragma unroll
    for (int i = 0; i < 20; i++) {
      int4 v = buf[i];
      int4 o;
      o.x = running;
      o.y = o.x + v.x;
      o.z = o.y + v.y;
      o.w = o.z + v.z;
      running = o.w + v.w;
      *(int4*)(a.offs + base + i * 4) = o;
      *(int4*)(a.cursor + base + i * 4) = o;
    }
  }
  if (t == 0) a.offs[N_NODES] = ET;
}

// ---------------- P3: CSR fill + attn1 (virtual blocks) ----------------------
static __device__ void phase_fill_attn(const Args& a, int bid, int tid) {
  const int wave = tid >> 6, lane = tid & 63;
  for (int vb = bid; vb < FILL_VB + ATTN_VB; vb += gridDim.x) {
    if (vb < FILL_VB) {
      int e = vb * 256 + tid;
      if (e < ET) {
        int src, dst;
        if (e < N_EDGES) { src = a.ei[e]; dst = a.ei[N_EDGES + e]; }
        else { src = e - N_EDGES; dst = src; }
        int pos = atomicAdd(&a.cursor[dst], 1);
        a.csr[pos] = src;
      }
    } else {
      int n = (vb - FILL_VB) * 4 + wave;       // 5000*4 == 20000, exact
      int c4 = lane * 4;
      uint2 raw = *(const uint2*)(a.h1b + (size_t)n * HH + c4);
      float h0 = bf2f_lo(raw.x), h1 = bf2f_hi(raw.x);
      float h2 = bf2f_lo(raw.y), h3 = bf2f_hi(raw.y);
      float4 sa = *(const float4*)(a.asrc1 + c4);
      float4 sd = *(const float4*)(a.adst1 + c4);
      float ps = h0 * sa.x + h1 * sa.y + h2 * sa.z + h3 * sa.w;
      float pd = h0 * sd.x + h1 * sd.y + h2 * sd.z + h3 * sd.w;
#pragma unroll
      for (int o = 4; o > 0; o >>= 1) {
        ps += __shfl_down(ps, o, 8);
        pd += __shfl_down(pd, o, 8);
      }
      if ((lane & 7) == 0) {
        a.as1[n * HEADS + (lane >> 3)] = ps;
        a.ad1[n * HEADS + (lane >> 3)] = pd;
      }
    }
  }
}

// ---------------- P4: agg1 + GEMM2(MFMA) + attn2, grid-stride tiles ----------
static __device__ void phase_layer1(const Args& a, int bid, int tid) {
  __shared__ __align__(16) unsigned short h2s[16][264];   // 8448 B
  __shared__ float psum[3][16], pdsum[3][16];
  const int wave = tid >> 6, lane = tid & 63;
  const int r16 = lane & 15, q = lane >> 4;

  // preload w2 B-fragments (invariant across tiles)
  short8 bfrag[8];
  float sa = 0.f, sd = 0.f, b2c = 0.f;
  if (wave < 3) {
    int col = wave * 16 + r16;
    int colc = (col < OUT_C) ? col : 0;
#pragma unroll
    for (int s = 0; s < 8; s++)
      bfrag[s] = *(const short8*)(a.w2bT + colc * HH + s * 32 + q * 8);
    if (col < OUT_C) { sa = a.asrc2[col]; sd = a.adst2[col]; b2c = a.b2[col]; }
  }
  const int half = lane >> 5, sl = lane & 31;
  const int c8 = sl * 8, head = sl >> 2;
  float4 b0 = *(const float4*)(a.b1 + c8);
  float4 b4 = *(const float4*)(a.b1 + c8 + 4);

  for (int tile = bid; tile < L1_TILES; tile += gridDim.x) {
    const int nodeBase = tile * 16;
    // ---- Phase A: gather (4 nodes per wave, half-split edge streams) ----
    for (int i = 0; i < 4; i++) {
      int local = wave * 4 + i;
      int n = nodeBase + local;
      int beg = a.offs[n], end = a.offs[n + 1];
      float ad = a.ad1[n * HEADS + head];
      float acc[8] = {};
      float l = 0.f;
#pragma unroll 2
      for (int k = beg + half; k < end; k += 2) {
        int src = a.csr[k];
        float e = a.as1[src * HEADS + head] + ad;
        e = (e > 0.f) ? e : NEG_SLOPE * e;
        float p = __expf(e);
        l += p;
        uint4 raw = *(const uint4*)(a.h1b + ((unsigned)src << 8) + c8);
        acc[0] = fmaf(p, bf2f_lo(raw.x), acc[0]);
        acc[1] = fmaf(p, bf2f_hi(raw.x), acc[1]);
        acc[2] = fmaf(p, bf2f_lo(raw.y), acc[2]);
        acc[3] = fmaf(p, bf2f_hi(raw.y), acc[3]);
        acc[4] = fmaf(p, bf2f_lo(raw.z), acc[4]);
        acc[5] = fmaf(p, bf2f_hi(raw.z), acc[5]);
        acc[6] = fmaf(p, bf2f_lo(raw.w), acc[6]);
        acc[7] = fmaf(p, bf2f_hi(raw.w), acc[7]);
      }
#pragma unroll
      for (int j = 0; j < 8; j++) acc[j] += __shfl_xor(acc[j], 32, 64);
      l += __shfl_xor(l, 32, 64);
      if (half == 0) {
        float li = 1.f / (l + 1e-16f);
        float v[8];
        v[0] = acc[0] * li + b0.x; v[1] = acc[1] * li + b0.y;
        v[2] = acc[2] * li + b0.z; v[3] = acc[3] * li + b0.w;
        v[4] = acc[4] * li + b4.x; v[5] = acc[5] * li + b4.y;
        v[6] = acc[6] * li + b4.z; v[7] = acc[7] * li + b4.w;
        unsigned short o8[8];
#pragma unroll
        for (int j = 0; j < 8; j++) {
          float e = (v[j] > 0.f) ? v[j] : expm1f(v[j]);   // ELU
          o8[j] = f2bf(e);
        }
        *(uint4*)&h2s[local][c8] = *(const uint4*)o8;
      }
    }
    __syncthreads();
    // ---- Phase B: MFMA [16 x 256] @ [256 x 48] + attn2 dots ----
    if (wave < 3) {
      floatx4 dacc = {};
#pragma unroll
      for (int s = 0; s < 8; s++) {
        short8 afrag = *(const short8*)&h2s[r16][s * 32 + q * 8];
        dacc = __builtin_amdgcn_mfma_f32_16x16x32_bf16(afrag, bfrag[s], dacc, 0, 0, 0);
      }
      int col = wave * 16 + r16;
      float psr[4], pdr[4];
#pragma unroll
      for (int r = 0; r < 4; r++) {
        float val = dacc[r] + b2c;
        if (col < OUT_C)
          a.h3[(size_t)(nodeBase + q * 4 + r) * OUT_C + col] = val;
        psr[r] = val * sa;
        pdr[r] = val * sd;
      }
#pragma unroll
      for (int o = 8; o > 0; o >>= 1) {
#pragma unroll
        for (int r = 0; r < 4; r++) {
          psr[r] += __shfl_down(psr[r], o, 16);
          pdr[r] += __shfl_down(pdr[r], o, 16);
        }
      }
      if (r16 == 0) {
#pragma unroll
        for (int r = 0; r < 4; r++) {
          psum[wave][q * 4 + r] = psr[r];
          pdsum[wave][q * 4 + r] = pdr[r];
        }
      }
    }
    __syncthreads();
    if (tid < 16) {
      a.as2[nodeBase + tid] = psum[0][tid] + psum[1][tid] + psum[2][tid];
      a.ad2[nodeBase + tid] = pdsum[0][tid] + pdsum[1][tid] + pdsum[2][tid];
    }
    __syncthreads();   // h2s/psum safe for next tile
  }
}

// ---------------- P5: agg2 (max-free softmax, dual-stream) + log_softmax -----
static __device__ void phase_agg2(const Args& a, int bid, int tid) {
  const int wave = tid >> 6, t = tid & 63;
  bool act = (t < OUT_C);
  for (int vb = bid; vb < AGG2_VB; vb += gridDim.x) {
    int n = vb * 4 + wave;
    int beg = a.offs[n], end = a.offs[n + 1];
    float ad = a.ad2[n];
    float l0 = 0.f, l1 = 0.f, a0 = 0.f, a1 = 0.f;
    int k = beg;
    for (; k + 1 < end; k += 2) {
      int s0 = a.csr[k], s1 = a.csr[k + 1];
      float e0 = a.as2[s0] + ad, e1 = a.as2[s1] + ad;
      e0 = (e0 > 0.f) ? e0 : NEG_SLOPE * e0;
      e1 = (e1 > 0.f) ? e1 : NEG_SLOPE * e1;
      float p0 = __expf(e0), p1 = __expf(e1);
      l0 += p0; l1 += p1;
      float h0 = act ? a.h3[(size_t)s0 * OUT_C + t] : 0.f;
      float h1 = act ? a.h3[(size_t)s1 * OUT_C + t] : 0.f;
      a0 = fmaf(p0, h0, a0);
      a1 = fmaf(p1, h1, a1);
    }
    if (k < end) {
      int s0 = a.csr[k];
      float e0 = a.as2[s0] + ad;
      e0 = (e0 > 0.f) ? e0 : NEG_SLOPE * e0;
      float p0 = __expf(e0);
      l0 += p0;
      float h0 = act ? a.h3[(size_t)s0 * OUT_C + t] : 0.f;
      a0 = fmaf(p0, h0, a0);
    }
    float l = l0 + l1, acc = a0 + a1;
    float v = acc / (l + 1e-16f) + (act ? a.b2[t] : 0.f);
    float x = act ? v : -INFINITY;
    float mx = x;
    for (int o = 32; o > 0; o >>= 1) mx = fmaxf(mx, __shfl_down(mx, o, 64));
    mx = __shfl(mx, 0, 64);
    float ex = act ? __expf(v - mx) : 0.f;
    float s = ex;
    for (int o = 32; o > 0; o >>= 1) s += __shfl_down(s, o, 64);
    s = __shfl(s, 0, 64);
    if (act) a.out[(size_t)n * OUT_C + t] = v - mx - logf(s);
  }
}

// ================= cooperative mega-kernel ===================================
__global__ __launch_bounds__(256, 4) void mega_kernel(Args a) {
  cg::grid_group g = cg::this_grid();
  const int bid = blockIdx.x, tid = threadIdx.x;
  phase_prep(a, bid, tid);
  g.sync();
  phase_gemm_count(a, bid, tid);
  g.sync();
  if (bid == 0) phase_scan(a, tid);
  g.sync();
  phase_fill_attn(a, bid, tid);
  g.sync();
  phase_layer1(a, bid, tid);
  g.sync();
  phase_agg2(a, bid, tid);
}

// ================= fallback kernels (plain launches) =========================
__global__ __launch_bounds__(256, 4) void k_prep(Args a) { phase_prep(a, blockIdx.x, threadIdx.x); }
__global__ __launch_bounds__(256, 4) void k_gemm(Args a) { phase_gemm_count(a, blockIdx.x, threadIdx.x); }
__global__ __launch_bounds__(256) void k_scan(Args a) { phase_scan(a, threadIdx.x); }
__global__ __launch_bounds__(256, 4) void k_fill(Args a) { phase_fill_attn(a, blockIdx.x, threadIdx.x); }
__global__ __launch_bounds__(256, 4) void k_layer1(Args a) { phase_layer1(a, blockIdx.x, threadIdx.x); }
__global__ __launch_bounds__(256, 4) void k_agg2(Args a) { phase_agg2(a, blockIdx.x, threadIdx.x); }

extern "C" void kernel_launch(void* const* d_in, const int* in_sizes, int n_in,
                              void* d_out, int out_size, void* d_ws, size_t ws_size,
                              hipStream_t stream) {
  Args a;
  a.x     = (const float*)d_in[0];
  a.ei    = (const int*)d_in[1];
  a.w1    = (const float*)d_in[2];
  a.asrc1 = (const float*)d_in[3];
  a.adst1 = (const float*)d_in[4];
  a.b1    = (const float*)d_in[5];
  a.w2    = (const float*)d_in[6];
  a.asrc2 = (const float*)d_in[7];
  a.adst2 = (const float*)d_in[8];
  a.b2    = (const float*)d_in[9];
  a.out   = (float*)d_out;

  float* fw = (float*)d_ws;
  a.as1 = fw;  fw += (size_t)N_NODES * HEADS;
  a.ad1 = fw;  fw += (size_t)N_NODES * HEADS;
  a.h3  = fw;  fw += (size_t)N_NODES * OUT_C;
  a.as2 = fw;  fw += N_NODES;
  a.ad2 = fw;  fw += N_NODES;
  a.h1b  = (unsigned short*)fw;  fw += (size_t)N_NODES * HH / 2;
  a.wbT  = (unsigned short*)fw;  fw += (size_t)IN_C * HH / 2;
  a.w2bT = (unsigned short*)fw;  fw += (size_t)HH * OUT_C / 2;
  a.deg    = (int*)fw;
  a.offs   = a.deg + N_NODES;          // N+1 (+3 pad)
  a.cursor = a.offs + N_NODES + 4;     // 16B-aligned
  a.csr    = a.cursor + N_NODES;       // ET

  // size the cooperative grid from occupancy (cap 4 blocks/CU x 256 CUs)
  int perCU = 0;
  hipError_t qerr = hipOccupancyMaxActiveBlocksPerMultiprocessor(
      &perCU, (const void*)mega_kernel, 256, 0);
  int grid = MAX_GRID;
  if (qerr == hipSuccess && perCU > 0) {
    int cap = perCU * 256;
    if (cap < grid) grid = cap;
  }

  void* params[] = {(void*)&a};
  hipError_t st = hipLaunchCooperativeKernel(
      (const void*)mega_kernel, dim3(grid), dim3(256), params, 0, stream);
  if (st != hipSuccess) {
    // fallback: same phases as 6 plain launches
    k_prep<<<MAX_GRID, 256, 0, stream>>>(a);
    k_gemm<<<MAX_GRID, 256, 0, stream>>>(a);
    k_scan<<<1, 256, 0, stream>>>(a);
    k_fill<<<MAX_GRID, 256, 0, stream>>>(a);
    k_layer1<<<MAX_GRID, 256, 0, stream>>>(a);
    k_agg2<<<MAX_GRID, 256, 0, stream>>>(a);
  }
}

// Round 13
// 251.543 us; speedup vs baseline: 2.3748x; 2.3748x over previous
//
#include <hip/hip_runtime.h>
#include <hip/hip_bf16.h>
#include <math.h>

#define N_NODES 20000
#define N_EDGES 320000
#define ET (N_EDGES + N_NODES)   // with self loops = 340000
#define IN_C 512
#define HEADS 8
#define HID 32
#define HH (HEADS * HID)         // 256
#define OUT_C 40
#define NEG_SLOPE 0.2f

typedef __attribute__((ext_vector_type(8))) short short8;
typedef __attribute__((ext_vector_type(4))) float floatx4;

static __device__ __forceinline__ unsigned short f2bf(float f) {
  __hip_bfloat16 h = __float2bfloat16(f);
  return *(unsigned short*)&h;
}
static __device__ __forceinline__ float bf2f_lo(unsigned int u) {
  return __uint_as_float(u << 16);
}
static __device__ __forceinline__ float bf2f_hi(unsigned int u) {
  return __uint_as_float(u & 0xFFFF0000u);
}

// ================= L1: w1/w2 -> bf16 (w2 transposed)  +  edge count ==========
#define WCONV_BLOCKS (IN_C * HH / 256)          // 512
#define W2CONV_BLOCKS (HH * OUT_C / 256)        // 40
#define COUNT_BLOCKS ((ET + 255) / 256)         // 1329
__global__ __launch_bounds__(256) void prep_kernel(
    const float* __restrict__ w1, const float* __restrict__ w2,
    const int* __restrict__ ei, unsigned short* __restrict__ wbT,
    unsigned short* __restrict__ w2bT, int* __restrict__ deg) {
  if (blockIdx.x < WCONV_BLOCKS) {
    int j = blockIdx.x * 256 + threadIdx.x;     // coalesced read of w1
    int k = j >> 8, n = j & 255;
    wbT[(size_t)n * IN_C + k] = f2bf(w1[j]);
  } else if (blockIdx.x < WCONV_BLOCKS + W2CONV_BLOCKS) {
    int j = (blockIdx.x - WCONV_BLOCKS) * 256 + threadIdx.x;  // 10240
    int k = j / OUT_C, oc = j % OUT_C;
    w2bT[oc * HH + k] = f2bf(w2[j]);
  } else {
    int e = (blockIdx.x - WCONV_BLOCKS - W2CONV_BLOCKS) * 256 + threadIdx.x;
    if (e < ET) {
      int dst = (e < N_EDGES) ? ei[N_EDGES + e] : (e - N_EDGES);
      atomicAdd(&deg[dst], 1);
    }
  }
}

// ================= L2: GEMM1 (MFMA bf16, f32 A staged+converted) + CSR scan ==
#define BM 64
#define BN 128
#define BK 32
#define APAD 40   // row stride in shorts (80B)
#define GY ((N_NODES + BM - 1) / BM)            // 313
#define GEMM_BLOCKS (2 * GY)                    // 626
__global__ __launch_bounds__(256) void gemm1_kernel(
    const float* __restrict__ X, const unsigned short* __restrict__ BT,
    const float* __restrict__ bias, unsigned short* __restrict__ C,
    const int* __restrict__ deg, int* __restrict__ offs, int* __restrict__ cursor) {
  if (blockIdx.x >= GEMM_BLOCKS) {
    // ---- CSR exclusive scan: 250 threads x 80 nodes, register-buffered ----
    __shared__ int wsum[4];
    int t = threadIdx.x;
    int4 buf[20];
    int s = 0;
    if (t < 250) {
      const int4* dp = (const int4*)deg + t * 20;
#pragma unroll
      for (int i = 0; i < 20; i++) {
        buf[i] = dp[i];
        s += buf[i].x + buf[i].y + buf[i].z + buf[i].w;
      }
    }
    int lane = t & 63, w = t >> 6;
    int inc = s;
    for (int o = 1; o < 64; o <<= 1) {
      int u = __shfl_up(inc, o, 64);
      if (lane >= o) inc += u;
    }
    if (lane == 63) wsum[w] = inc;
    __syncthreads();
    int waveOff = 0;
    for (int i = 0; i < w; i++) waveOff += wsum[i];
    int running = waveOff + inc - s;
    if (t < 250) {
      int base = t * 80;
#pragma unroll
      for (int i = 0; i < 20; i++) {
        int4 v = buf[i];
        int4 o;
        o.x = running;
        o.y = o.x + v.x;
        o.z = o.y + v.y;
        o.w = o.z + v.z;
        running = o.w + v.w;
        *(int4*)(offs + base + i * 4) = o;
        *(int4*)(cursor + base + i * 4) = o;
      }
    }
    if (t == 0) offs[N_NODES] = ET;
    return;
  }
  // ---- GEMM tile ----
  __shared__ unsigned short As[BM][APAD];
  __shared__ unsigned short Bs[BN][APAD];
  const int tid = threadIdx.x;
  const int lane = tid & 63, wave = tid >> 6;
  const int wm = (wave & 1) * 32;
  const int wn = (wave >> 1) * 64;
  const int r16 = lane & 15, q = lane >> 4;
  const int bx = blockIdx.x & 1, by = blockIdx.x >> 1;
  const int rowBase = by * BM;
  const int colBase = bx * BN;
  floatx4 acc[2][4] = {};

  for (int k0 = 0; k0 < IN_C; k0 += BK) {
    {
      int row = tid >> 2, kc = (tid & 3) * 8;
      int arow = rowBase + row;
      float4 v0 = make_float4(0.f, 0.f, 0.f, 0.f), v1 = v0;
      if (arow < N_NODES) {
        const float* p = X + (size_t)arow * IN_C + k0 + kc;
        v0 = *(const float4*)p;
        v1 = *(const float4*)(p + 4);
      }
      unsigned short tmp[8] = {f2bf(v0.x), f2bf(v0.y), f2bf(v0.z), f2bf(v0.w),
                               f2bf(v1.x), f2bf(v1.y), f2bf(v1.z), f2bf(v1.w)};
      *(float4*)&As[row][kc] = *(const float4*)tmp;
    }
#pragma unroll
    for (int i = 0; i < 2; i++) {
      int c = tid + i * 256;
      int row = c >> 2, kc = (c & 3) * 8;
      float4 v = *(const float4*)(BT + (size_t)(colBase + row) * IN_C + k0 + kc);
      *(float4*)&Bs[row][kc] = v;
    }
    __syncthreads();
    short8 afrag[2], bfrag[4];
#pragma unroll
    for (int mt = 0; mt < 2; mt++)
      afrag[mt] = *(const short8*)&As[wm + mt * 16 + r16][q * 8];
#pragma unroll
    for (int nt = 0; nt < 4; nt++)
      bfrag[nt] = *(const short8*)&Bs[wn + nt * 16 + r16][q * 8];
#pragma unroll
    for (int mt = 0; mt < 2; mt++)
#pragma unroll
      for (int nt = 0; nt < 4; nt++)
        acc[mt][nt] = __builtin_amdgcn_mfma_f32_16x16x32_bf16(
            afrag[mt], bfrag[nt], acc[mt][nt], 0, 0, 0);
    __syncthreads();
  }
#pragma unroll
  for (int mt = 0; mt < 2; mt++) {
#pragma unroll
    for (int nt = 0; nt < 4; nt++) {
      int col = colBase + wn + nt * 16 + r16;
      float bb = bias[col];
#pragma unroll
      for (int r = 0; r < 4; r++) {
        int row = rowBase + wm + mt * 16 + q * 4 + r;
        if (row < N_NODES) C[(size_t)row * HH + col] = f2bf(acc[mt][nt][r] + bb);
      }
    }
  }
}

// ================= L3: CSR fill + attn1 (wave-per-node dots) =================
#define FILL_BLOCKS ((ET + 255) / 256)          // 1329
#define ATTN1_BLOCKS (N_NODES / 4)              // 5000
__global__ __launch_bounds__(256) void fill_attn1_kernel(
    const int* __restrict__ ei, int* __restrict__ cursor, int* __restrict__ csr,
    const unsigned short* __restrict__ h1b, const float* __restrict__ asrc,
    const float* __restrict__ adst, float* __restrict__ as1, float* __restrict__ ad1) {
  if (blockIdx.x < FILL_BLOCKS) {
    int e = blockIdx.x * 256 + threadIdx.x;
    if (e >= ET) return;
    int src, dst;
    if (e < N_EDGES) { src = ei[e]; dst = ei[N_EDGES + e]; }
    else { src = e - N_EDGES; dst = src; }
    int pos = atomicAdd(&cursor[dst], 1);
    csr[pos] = src;
  } else {
    int wave = threadIdx.x >> 6, lane = threadIdx.x & 63;
    int n = (blockIdx.x - FILL_BLOCKS) * 4 + wave;   // exact: 5000*4 = 20000
    int c4 = lane * 4;
    uint2 raw = *(const uint2*)(h1b + (size_t)n * HH + c4);
    float h0 = bf2f_lo(raw.x), h1 = bf2f_hi(raw.x);
    float h2 = bf2f_lo(raw.y), h3 = bf2f_hi(raw.y);
    float4 sa = *(const float4*)(asrc + c4);
    float4 sd = *(const float4*)(adst + c4);
    float ps = h0 * sa.x + h1 * sa.y + h2 * sa.z + h3 * sa.w;
    float pd = h0 * sd.x + h1 * sd.y + h2 * sd.z + h3 * sd.w;
#pragma unroll
    for (int o = 4; o > 0; o >>= 1) {
      ps += __shfl_down(ps, o, 8);
      pd += __shfl_down(pd, o, 8);
    }
    if ((lane & 7) == 0) {
      as1[n * HEADS + (lane >> 3)] = ps;
      ad1[n * HEADS + (lane >> 3)] = pd;
    }
  }
}

// ================= L4: SEGMENTED agg1 + GEMM2(MFMA) + attn2 ==================
// Block = 32 dst nodes. Phase A: 16 groups of 16 lanes; each group walks a
// CONTIGUOUS chunk of the block's CSR edges, accumulating p*h in REGISTERS
// (per-head p; per-head lacc) and flushing to LDS atomics only on dst-row
// change (~2 atomics/edge). Per-(node,head) normalizer lsum8. Then
// normalize+bias+ELU->bf16 in LDS; MFMA phase B; attn2 dots.
#define NPB1 32
#define AROW 260     // f32 accumulator row stride
#define H2ROW 264    // bf16 row stride (reuses h2acc storage)
__global__ __launch_bounds__(256) void layer1_fused_kernel(
    const unsigned short* __restrict__ h1b, const float* __restrict__ as1,
    const float* __restrict__ ad1, const int* __restrict__ offs,
    const int* __restrict__ csr, const float* __restrict__ b1,
    const unsigned short* __restrict__ w2bT, const float* __restrict__ b2,
    const float* __restrict__ asrc2, const float* __restrict__ adst2,
    float* __restrict__ h3, float* __restrict__ as2, float* __restrict__ ad2) {
  __shared__ __align__(16) float h2acc[NPB1][AROW];   // 33280 B (reused as bf16)
  __shared__ float lsum8[NPB1][HEADS];                // per-(node,head) l
  __shared__ int soffs[NPB1 + 1];
  __shared__ float adc[NPB1 * HEADS];
  __shared__ float psum[3][NPB1], pdsum[3][NPB1];
  const int tid = threadIdx.x;
  const int d0 = blockIdx.x * NPB1;

  // init LDS
  for (int i = tid; i < NPB1 * AROW; i += 256) ((float*)h2acc)[i] = 0.f;
  ((float*)lsum8)[tid] = 0.f;                   // 32*8 == 256
  if (tid <= NPB1) soffs[tid] = offs[d0 + tid];
  adc[tid] = ad1[d0 * HEADS + tid];             // [local*8 + head]
  __syncthreads();

  // ---- Phase A: segmented reduction over contiguous edge chunks ----
  {
    const int grp = tid >> 4;                   // 0..15
    const int sub = tid & 15;                   // lane within group
    const int head = sub >> 1;
    const int ch16 = sub * 16;
    const int e0 = soffs[0], e1 = soffs[NPB1];
    const int chunk = (e1 - e0 + 15) >> 4;
    int myBeg = e0 + grp * chunk;
    int myEnd = myBeg + chunk;
    if (myEnd > e1) myEnd = e1;
    if (myBeg < myEnd) {
      // initial row: soffs[lo] <= myBeg < soffs[lo+1]
      int lo = 0, hi = NPB1;
      while (hi - lo > 1) {
        int mid = (lo + hi) >> 1;
        if (soffs[mid] <= myBeg) lo = mid; else hi = mid;
      }
      int bound = soffs[lo + 1];
      float acc[16] = {};
      float lacc = 0.f;
      // software pipeline: one edge ahead
      int src = csr[myBeg];
      const unsigned short* hp = h1b + ((unsigned)src << 8) + ch16;
      uint4 r0 = *(const uint4*)hp;
      uint4 r1 = *(const uint4*)(hp + 8);
      float as = as1[src * HEADS + head];
      for (int e = myBeg; e < myEnd; e++) {
        int en = e + 1;
        uint4 n0, n1;
        float nas = 0.f;
        if (en < myEnd) {
          int nsrc = csr[en];
          const unsigned short* np = h1b + ((unsigned)nsrc << 8) + ch16;
          n0 = *(const uint4*)np;
          n1 = *(const uint4*)(np + 8);
          nas = as1[nsrc * HEADS + head];
        } else {
          n0 = make_uint4(0, 0, 0, 0);
          n1 = make_uint4(0, 0, 0, 0);
        }
        if (e >= bound) {                       // dst row finished -> flush
          float* arow = &h2acc[lo][ch16];
#pragma unroll
          for (int j = 0; j < 16; j++) atomicAdd(&arow[j], acc[j]);
          if ((sub & 1) == 0) atomicAdd(&lsum8[lo][head], lacc);
#pragma unroll
          for (int j = 0; j < 16; j++) acc[j] = 0.f;
          lacc = 0.f;
          lo++;
          while (soffs[lo + 1] <= e) lo++;
          bound = soffs[lo + 1];
        }
        float x = as + adc[lo * HEADS + head];
        x = (x > 0.f) ? x : NEG_SLOPE * x;
        float p = __expf(x);
        lacc += p;
        acc[0]  = fmaf(p, bf2f_lo(r0.x), acc[0]);
        acc[1]  = fmaf(p, bf2f_hi(r0.x), acc[1]);
        acc[2]  = fmaf(p, bf2f_lo(r0.y), acc[2]);
        acc[3]  = fmaf(p, bf2f_hi(r0.y), acc[3]);
        acc[4]  = fmaf(p, bf2f_lo(r0.z), acc[4]);
        acc[5]  = fmaf(p, bf2f_hi(r0.z), acc[5]);
        acc[6]  = fmaf(p, bf2f_lo(r0.w), acc[6]);
        acc[7]  = fmaf(p, bf2f_hi(r0.w), acc[7]);
        acc[8]  = fmaf(p, bf2f_lo(r1.x), acc[8]);
        acc[9]  = fmaf(p, bf2f_hi(r1.x), acc[9]);
        acc[10] = fmaf(p, bf2f_lo(r1.y), acc[10]);
        acc[11] = fmaf(p, bf2f_hi(r1.y), acc[11]);
        acc[12] = fmaf(p, bf2f_lo(r1.z), acc[12]);
        acc[13] = fmaf(p, bf2f_hi(r1.z), acc[13]);
        acc[14] = fmaf(p, bf2f_lo(r1.w), acc[14]);
        acc[15] = fmaf(p, bf2f_hi(r1.w), acc[15]);
        r0 = n0; r1 = n1; as = nas;
      }
      // final flush
      float* arow = &h2acc[lo][ch16];
#pragma unroll
      for (int j = 0; j < 16; j++) atomicAdd(&arow[j], acc[j]);
      if ((sub & 1) == 0) atomicAdd(&lsum8[lo][head], lacc);
    }
  }
  __syncthreads();

  // ---- normalize + bias + ELU -> bf16 (in-place LDS reuse) ----
  {
    const int row = tid >> 3;                   // 32 rows
    const int g = tid & 7;                      // 32-ch group == head
    float vals[32];
#pragma unroll
    for (int j = 0; j < 32; j++) vals[j] = h2acc[row][g * 32 + j];
    float li = 1.f / (lsum8[row][g] + 1e-16f);  // per-(node,head) normalizer
    unsigned short o32[32];
#pragma unroll
    for (int j = 0; j < 32; j++) {
      float v = vals[j] * li + b1[g * 32 + j];
      v = (v > 0.f) ? v : expm1f(v);            // ELU
      o32[j] = f2bf(v);
    }
    __syncthreads();
    unsigned short* h2s = (unsigned short*)h2acc;
#pragma unroll
    for (int j = 0; j < 4; j++)
      *(uint4*)&h2s[row * H2ROW + g * 32 + j * 8] = *(const uint4*)&o32[j * 8];
  }
  __syncthreads();

  // ---- Phase B: MFMA [32 x 256] @ [256 x 48], 6 jobs over 4 waves ----
  {
    const int wave = tid >> 6, lane = tid & 63;
    const int r16 = lane & 15, q = lane >> 4;
    const unsigned short* h2s = (const unsigned short*)h2acc;
    for (int job = wave; job < 6; job += 4) {
      int rt = job / 3, ct = job % 3;
      int col = ct * 16 + r16;
      int colc = (col < OUT_C) ? col : 0;
      float sa = 0.f, sd = 0.f, b2c = 0.f;
      if (col < OUT_C) { sa = asrc2[col]; sd = adst2[col]; b2c = b2[col]; }
      floatx4 dacc = {};
#pragma unroll
      for (int s = 0; s < 8; s++) {
        short8 bfrag = *(const short8*)(w2bT + colc * HH + s * 32 + q * 8);
        short8 afrag = *(const short8*)&h2s[(rt * 16 + r16) * H2ROW + s * 32 + q * 8];
        dacc = __builtin_amdgcn_mfma_f32_16x16x32_bf16(afrag, bfrag, dacc, 0, 0, 0);
      }
      float psr[4], pdr[4];
#pragma unroll
      for (int r = 0; r < 4; r++) {
        float val = dacc[r] + b2c;
        if (col < OUT_C)
          h3[(size_t)(d0 + rt * 16 + q * 4 + r) * OUT_C + col] = val;
        psr[r] = val * sa;
        pdr[r] = val * sd;
      }
#pragma unroll
      for (int o = 8; o > 0; o >>= 1) {
#pragma unroll
        for (int r = 0; r < 4; r++) {
          psr[r] += __shfl_down(psr[r], o, 16);
          pdr[r] += __shfl_down(pdr[r], o, 16);
        }
      }
      if (r16 == 0) {
#pragma unroll
        for (int r = 0; r < 4; r++) {
          psum[ct][rt * 16 + q * 4 + r] = psr[r];
          pdsum[ct][rt * 16 + q * 4 + r] = pdr[r];
        }
      }
    }
  }
  __syncthreads();
  if (tid < NPB1) {
    as2[d0 + tid] = psum[0][tid] + psum[1][tid] + psum[2][tid];
    ad2[d0 + tid] = pdsum[0][tid] + pdsum[1][tid] + pdsum[2][tid];
  }
}

// ================= L5: agg2 (max-free softmax, dual-stream) + log_softmax ====
__global__ __launch_bounds__(256) void agg2_kernel(
    const float* __restrict__ h3, const float* __restrict__ as2,
    const float* __restrict__ ad2, const int* __restrict__ offs,
    const int* __restrict__ csr, const float* __restrict__ b2,
    float* __restrict__ out) {
  int n = blockIdx.x * 4 + (threadIdx.x >> 6);
  int t = threadIdx.x & 63;
  bool act = (t < OUT_C);
  int beg = offs[n], end = offs[n + 1];
  float ad = ad2[n];
  float l0 = 0.f, l1 = 0.f, a0 = 0.f, a1 = 0.f;
  int k = beg;
  for (; k + 1 < end; k += 2) {
    int s0 = csr[k], s1 = csr[k + 1];
    float e0 = as2[s0] + ad, e1 = as2[s1] + ad;
    e0 = (e0 > 0.f) ? e0 : NEG_SLOPE * e0;
    e1 = (e1 > 0.f) ? e1 : NEG_SLOPE * e1;
    float p0 = __expf(e0), p1 = __expf(e1);
    l0 += p0; l1 += p1;
    float h0 = act ? h3[(size_t)s0 * OUT_C + t] : 0.f;
    float h1 = act ? h3[(size_t)s1 * OUT_C + t] : 0.f;
    a0 = fmaf(p0, h0, a0);
    a1 = fmaf(p1, h1, a1);
  }
  if (k < end) {
    int s0 = csr[k];
    float e0 = as2[s0] + ad;
    e0 = (e0 > 0.f) ? e0 : NEG_SLOPE * e0;
    float p0 = __expf(e0);
    l0 += p0;
    float h0 = act ? h3[(size_t)s0 * OUT_C + t] : 0.f;
    a0 = fmaf(p0, h0, a0);
  }
  float l = l0 + l1, acc = a0 + a1;
  float v = acc / (l + 1e-16f) + (act ? b2[t] : 0.f);
  float x = act ? v : -INFINITY;
  float mx = x;
  for (int o = 32; o > 0; o >>= 1) mx = fmaxf(mx, __shfl_down(mx, o, 64));
  mx = __shfl(mx, 0, 64);
  float ex = act ? __expf(v - mx) : 0.f;
  float s = ex;
  for (int o = 32; o > 0; o >>= 1) s += __shfl_down(s, o, 64);
  s = __shfl(s, 0, 64);
  if (act) out[(size_t)n * OUT_C + t] = v - mx - logf(s);
}

extern "C" void kernel_launch(void* const* d_in, const int* in_sizes, int n_in,
                              void* d_out, int out_size, void* d_ws, size_t ws_size,
                              hipStream_t stream) {
  const float* x     = (const float*)d_in[0];
  const int*   ei    = (const int*)d_in[1];
  const float* w1    = (const float*)d_in[2];
  const float* asrc1 = (const float*)d_in[3];
  const float* adst1 = (const float*)d_in[4];
  const float* b1    = (const float*)d_in[5];
  const float* w2    = (const float*)d_in[6];
  const float* asrc2 = (const float*)d_in[7];
  const float* adst2 = (const float*)d_in[8];
  const float* b2    = (const float*)d_in[9];
  float* out = (float*)d_out;

  // workspace carve-up. All extents keep 16B alignment.
  float* fw = (float*)d_ws;
  float* as1   = fw;  fw += (size_t)N_NODES * HEADS;
  float* ad1   = fw;  fw += (size_t)N_NODES * HEADS;
  float* h3    = fw;  fw += (size_t)N_NODES * OUT_C;
  float* as2   = fw;  fw += N_NODES;
  float* ad2   = fw;  fw += N_NODES;
  unsigned short* h1b  = (unsigned short*)fw;  fw += (size_t)N_NODES * HH / 2;
  unsigned short* wbT  = (unsigned short*)fw;  fw += (size_t)IN_C * HH / 2;
  unsigned short* w2bT = (unsigned short*)fw;  fw += (size_t)HH * OUT_C / 2;
  int* deg    = (int*)fw;
  int* offs   = deg + N_NODES;            // N+1 (+3 pad)
  int* cursor = offs + N_NODES + 4;       // 16B-aligned
  int* csr    = cursor + N_NODES;         // ET

  hipMemsetAsync(deg, 0, N_NODES * sizeof(int), stream);

  prep_kernel<<<WCONV_BLOCKS + W2CONV_BLOCKS + COUNT_BLOCKS, 256, 0, stream>>>(
      w1, w2, ei, wbT, w2bT, deg);
  gemm1_kernel<<<GEMM_BLOCKS + 1, 256, 0, stream>>>(x, wbT, b1, h1b, deg, offs, cursor);
  fill_attn1_kernel<<<FILL_BLOCKS + ATTN1_BLOCKS, 256, 0, stream>>>(
      ei, cursor, csr, h1b, asrc1, adst1, as1, ad1);
  layer1_fused_kernel<<<N_NODES / NPB1, 256, 0, stream>>>(
      h1b, as1, ad1, offs, csr, b1, w2bT, b2, asrc2, adst2, h3, as2, ad2);
  agg2_kernel<<<N_NODES / 4, 256, 0, stream>>>(h3, as2, ad2, offs, csr, b2, out);
}